// Round 1
// baseline (1397.659 us; speedup 1.0000x reference)
//
#include <hip/hip_runtime.h>
#include <hip/hip_bf16.h>

#define RES 512
#define CHAN 16
#define HW (RES * RES)          // 262144
#define PLANE_F (CHAN * HW)     // floats per plane, original layout
#define PLANE_T (HW * CHAN)     // floats per plane, transposed layout (same count)

// ---------------------------------------------------------------------------
// Pass 1: transpose (3, 16, 512, 512) -> (3, 512, 512, 16) so that the 16
// channels at one (h,w) are a contiguous 64B block (4 x float4).
// Block = 256 threads handles one (plane, h, 256-wide w strip).
// Reads are fully coalesced (lanes over w); writes are 4 float4 stores per
// thread at 64B lane stride — L2 write-combines them into full lines.
// ---------------------------------------------------------------------------
__global__ __launch_bounds__(256) void triplane_transpose(
    const float* __restrict__ src, float* __restrict__ dst) {
  int b   = blockIdx.x;
  int p   = b >> 10;            // 1024 blocks per plane (512 h * 2 strips)
  int rem = b & 1023;
  int h   = rem >> 1;
  int w   = ((rem & 1) << 8) + threadIdx.x;

  float v[CHAN];
#pragma unroll
  for (int c = 0; c < CHAN; ++c)
    v[c] = src[(size_t)(p * CHAN + c) * HW + h * RES + w];

  float4* dst4 = (float4*)dst + ((size_t)(p * RES + h) * RES + w) * 4;
#pragma unroll
  for (int j = 0; j < 4; ++j)
    dst4[j] = make_float4(v[4 * j + 0], v[4 * j + 1], v[4 * j + 2], v[4 * j + 3]);
}

// ---------------------------------------------------------------------------
// Pass 2: one thread per (point, channel-quad).  gid = p*12 + q.
//   q/4 == 0 -> f_xy : plane 0, coords (x, y)
//   q/4 == 1 -> f_yz : plane 2, coords (y, z/0.05)
//   q/4 == 2 -> f_zx : plane 1, coords (z/0.05, x)
// Each thread: 4 corner float4 gathers + 1 perfectly-coalesced float4 store.
// ---------------------------------------------------------------------------
template <bool TRANSPOSED>
__global__ __launch_bounds__(256) void triplane_gather(
    const float* __restrict__ xyz, const float* __restrict__ fm,
    float* __restrict__ out, int n12) {
  int gid = blockIdx.x * 256 + threadIdx.x;
  if (gid >= n12) return;

  int p  = gid / 12;                  // umulhi under the hood
  int q  = gid - p * 12;
  int s  = q >> 2;                    // segment 0,1,2
  int cq = q & 3;                     // channel quad

  float x = xyz[p * 3 + 0];
  float y = xyz[p * 3 + 1];
  float z = xyz[p * 3 + 2];
  float zs = z / 0.05f;               // match reference's division semantics

  // branchless plane/coord select
  float a  = (s == 0) ? x : ((s == 1) ? y : zs);
  float b  = (s == 0) ? y : ((s == 1) ? zs : x);
  int   pl = (s == 0) ? 0 : ((s == 1) ? 2 : 1);

  float u = (a + 1.0f) * 255.5f;      // (D0-1)*0.5, D0 = 512
  float v = (b + 1.0f) * 255.5f;

  float x0 = floorf(u), y0 = floorf(v);
  float x1 = x0 + 1.0f, y1 = y0 + 1.0f;

  float wa = (x1 - u) * (y1 - v);
  float wb = (u - x0) * (y1 - v);
  float wc = (x1 - u) * (v - y0);
  float wd = (u - x0) * (v - y0);

  int x0i = (int)fminf(fmaxf(x0, 0.0f), 510.0f);
  int x1i = (int)fminf(fmaxf(x1, 1.0f), 511.0f);
  int y0i = (int)fminf(fmaxf(y0, 0.0f), 510.0f);
  int y1i = (int)fminf(fmaxf(y1, 1.0f), 511.0f);

  float4 r;
  if (TRANSPOSED) {
    const float4* base = (const float4*)fm + (size_t)pl * (PLANE_T / 4);
    float4 A = base[(size_t)(x0i * RES + y0i) * 4 + cq];
    float4 B = base[(size_t)(x1i * RES + y0i) * 4 + cq];
    float4 C = base[(size_t)(x0i * RES + y1i) * 4 + cq];
    float4 D = base[(size_t)(x1i * RES + y1i) * 4 + cq];
    r.x = wa * A.x + wb * B.x + wc * C.x + wd * D.x;
    r.y = wa * A.y + wb * B.y + wc * C.y + wd * D.y;
    r.z = wa * A.z + wb * B.z + wc * C.z + wd * D.z;
    r.w = wa * A.w + wb * B.w + wc * C.w + wd * D.w;
  } else {
    // fallback: gather from original (C,H,W) layout (channel stride 1MB)
    const float* base = fm + (size_t)pl * PLANE_F + (size_t)(cq * 4) * HW;
    float acc[4];
#pragma unroll
    for (int j = 0; j < 4; ++j) {
      const float* ch = base + (size_t)j * HW;
      float A = ch[x0i * RES + y0i];
      float B = ch[x1i * RES + y0i];
      float C = ch[x0i * RES + y1i];
      float D = ch[x1i * RES + y1i];
      acc[j] = wa * A + wb * B + wc * C + wd * D;
    }
    r = make_float4(acc[0], acc[1], acc[2], acc[3]);
  }

  ((float4*)out)[gid] = r;
}

extern "C" void kernel_launch(void* const* d_in, const int* in_sizes, int n_in,
                              void* d_out, int out_size, void* d_ws, size_t ws_size,
                              hipStream_t stream) {
  const float* xyz = (const float*)d_in[0];
  const float* fm  = (const float*)d_in[1];
  float* out = (float*)d_out;

  int N   = in_sizes[0] / 3;
  int n12 = N * 12;
  int grid = (n12 + 255) / 256;

  size_t need = (size_t)3 * PLANE_T * sizeof(float);  // 48 MB
  if (ws_size >= need) {
    triplane_transpose<<<3 * 1024, 256, 0, stream>>>(fm, (float*)d_ws);
    triplane_gather<true><<<grid, 256, 0, stream>>>(xyz, (const float*)d_ws, out, n12);
  } else {
    triplane_gather<false><<<grid, 256, 0, stream>>>(xyz, fm, out, n12);
  }
}